// Round 10
// baseline (287.842 us; speedup 1.0000x reference)
//
#include <hip/hip_runtime.h>
#include <hip/hip_bf16.h>

#define B_   16384
#define F_   26
#define N_   100000
#define M_   16
#define NUM_ 13
#define D_   429
#define KP1_ 448     // padded K for GEMM1 (bf16 operand), multiple of 64
#define L_   6
#define H_   1024

typedef unsigned short u16;
typedef __bf16 bf16x8 __attribute__((ext_vector_type(8)));
typedef float  f32x4  __attribute__((ext_vector_type(4)));

__device__ __forceinline__ u16 f2bf_bits(float f) {
  union { float f; unsigned u; } x; x.f = f;
  unsigned r = x.u + 0x7FFFu + ((x.u >> 16) & 1u);   // RNE
  return (u16)(r >> 16);
}

// Fused front kernel. Tail of the final dot now goes to tailbuf (idempotent chain).
__global__ __launch_bounds__(256) void fused_front(
    const int* __restrict__ Xi, const float* __restrict__ Xv,
    const float* __restrict__ emb,
    const float* __restrict__ cw, const float* __restrict__ cb,
    const float* __restrict__ Wout, const float* __restrict__ bout,
    const float* __restrict__ W1, const float* __restrict__ W2,
    u16* __restrict__ x0b, u16* __restrict__ w1bt, u16* __restrict__ w2bt,
    float* __restrict__ tailbuf) {
  __shared__ __align__(16) u16 sbuf[4][KP1_];
  __shared__ __align__(16) float tile[64][68];
  const int blk = blockIdx.x;
  const int tid = threadIdx.x;
  if (blk < B_ / 4) {
    const int w = tid >> 6, lane = tid & 63;
    const int b = blk * 4 + w;
    const int* xi = Xi + b * F_;

    float x0r[7];
    #pragma unroll
    for (int i = 0; i < 7; ++i) {
      int e = i * 64 + lane;
      float v = 0.f;
      if (e < 416) {
        int f = e >> 4;
        int idx = xi[f];
        v = emb[((size_t)f * N_ + idx) * M_ + (e & 15)];
      } else if (e < D_) {
        v = Xv[b * NUM_ + (e - 416)];
      }
      x0r[i] = v;
      sbuf[w][e] = f2bf_bits(v);
    }

    float xr[7];
    #pragma unroll
    for (int i = 0; i < 7; ++i) xr[i] = x0r[i];
    for (int l = 0; l < L_; ++l) {
      float wl[7], bl[7];
      #pragma unroll
      for (int i = 0; i < 7; ++i) {
        int e = i * 64 + lane;
        if (e < D_) {
          int d = (e < 416) ? (13 + e) : (e - 416);
          wl[i] = cw[l * D_ + d]; bl[i] = cb[l * D_ + d];
        } else { wl[i] = 0.f; bl[i] = 0.f; }
      }
      float s = 0.f;
      #pragma unroll
      for (int i = 0; i < 7; ++i) s += xr[i] * wl[i];
      #pragma unroll
      for (int off = 32; off; off >>= 1) s += __shfl_xor(s, off);
      #pragma unroll
      for (int i = 0; i < 7; ++i) xr[i] = x0r[i] * s + bl[i] + xr[i];
    }

    __syncthreads();
    if (lane < 56)
      ((uint4*)(x0b + (size_t)b * KP1_))[lane] = ((const uint4*)sbuf[w])[lane];

    float s = 0.f;
    #pragma unroll
    for (int i = 0; i < 7; ++i) {
      int e = i * 64 + lane;
      if (e < D_) {
        int d = (e < 416) ? (13 + e) : (e - 416);
        s += xr[i] * Wout[H_ + d];
      }
    }
    #pragma unroll
    for (int off = 32; off; off >>= 1) s += __shfl_xor(s, off);
    if (lane == 0) tailbuf[b] = s + bout[0];
  } else {
    int pid = blk - B_ / 4;
    if (pid < 112) {
      const int ti = pid >> 4, tj = pid & 15;
      const int e0 = ti * 64, c0 = tj * 64;
      #pragma unroll
      for (int it = 0; it < 4; ++it) {
        int el = it * 16 + (tid >> 4);
        int e = e0 + el;
        int d = (e < 416) ? (13 + e) : ((e < D_) ? (e - 416) : -1);
        float4 v = make_float4(0.f, 0.f, 0.f, 0.f);
        if (d >= 0) v = *(const float4*)&W1[(size_t)d * H_ + c0 + (tid & 15) * 4];
        *(float4*)&tile[el][(tid & 15) * 4] = v;
      }
      __syncthreads();
      const int nl = tid >> 2, ks = (tid & 3) * 16;
      u16 tmp[16];
      #pragma unroll
      for (int x = 0; x < 16; ++x) tmp[x] = f2bf_bits(tile[ks + x][nl]);
      uint4* dst = (uint4*)&w1bt[(size_t)(c0 + nl) * KP1_ + e0 + ks];
      dst[0] = *(uint4*)&tmp[0];
      dst[1] = *(uint4*)&tmp[8];
    } else {
      pid -= 112;
      const int ti = pid >> 4, tj = pid & 15;
      const int k0 = ti * 64, c0 = tj * 64;
      #pragma unroll
      for (int it = 0; it < 4; ++it) {
        int kl = it * 16 + (tid >> 4);
        *(float4*)&tile[kl][(tid & 15) * 4] =
            *(const float4*)&W2[(size_t)(k0 + kl) * H_ + c0 + (tid & 15) * 4];
      }
      __syncthreads();
      const int nl = tid >> 2, ks = (tid & 3) * 16;
      u16 tmp[16];
      #pragma unroll
      for (int x = 0; x < 16; ++x) tmp[x] = f2bf_bits(tile[ks + x][nl]);
      uint4* dst = (uint4*)&w2bt[(size_t)(c0 + nl) * H_ + k0 + ks];
      dst[0] = *(uint4*)&tmp[0];
      dst[1] = *(uint4*)&tmp[8];
    }
  }
}

#define BARR __builtin_amdgcn_s_barrier()
#define VM6  asm volatile("s_waitcnt vmcnt(6)" ::: "memory")
#define VM0  asm volatile("s_waitcnt vmcnt(0)" ::: "memory")
#define MM(ACC) do { \
  __builtin_amdgcn_s_setprio(1); \
  _Pragma("unroll") \
  for (int mi = 0; mi < 4; ++mi) { \
    _Pragma("unroll") \
    for (int ni = 0; ni < 4; ++ni) \
      ACC[mi][ni] = __builtin_amdgcn_mfma_f32_16x16x32_bf16(af[mi], bfc[ni], ACC[mi][ni], 0, 0, 0); \
  } \
  __builtin_amdgcn_s_setprio(0); \
} while (0)

// r7 GEMM verbatim (best measured: 94.6 us), except MODE 1 writes idempotent
// per-(bx,wc) partials instead of atomicAdd.
template<int MODE>
__global__ __launch_bounds__(512, 2) void gemm256(
    const u16* __restrict__ A, const u16* __restrict__ BT,
    const float* __restrict__ bias, u16* __restrict__ C,
    const float* __restrict__ Wout, float* __restrict__ part,
    int N, int K) {
  __shared__ __align__(16) u16 As[2][2][256 * 32];
  __shared__ __align__(16) u16 Bs[2][2][256 * 32];
  const int nbx = N >> 8;
  const int cpx = gridDim.x >> 3;
  const int swz = (blockIdx.x & 7) * cpx + (blockIdx.x >> 3);
  const int bx = swz % nbx;
  const int by = swz / nbx;
  const int tid = threadIdx.x;
  const int l = tid & 63;
  const int w = tid >> 6;
  const int wr = w >> 2, wc = w & 3;
  const int nkt = K >> 6;

  const int sr = tid >> 2;
  const int scs = ((tid & 3) ^ ((tid >> 3) & 3)) * 8;
  const u16* gA0 = A  + (size_t)(by * 256 + sr) * K + scs;
  const u16* gB0 = BT + (size_t)(bx * 256 + sr) * K + scs;
  const int dst0 = tid * 8;

  auto stgA = [&](int t, int kk) {
    const u16* s = gA0 + t * 64 + kk * 32;
    __builtin_amdgcn_global_load_lds(
        (const __attribute__((address_space(1))) void*)s,
        (__attribute__((address_space(3))) void*)&As[t & 1][kk][dst0], 16, 0, 0);
    __builtin_amdgcn_global_load_lds(
        (const __attribute__((address_space(1))) void*)(s + (size_t)128 * K),
        (__attribute__((address_space(3))) void*)&As[t & 1][kk][dst0 + 4096], 16, 0, 0);
  };
  auto stgB = [&](int t, int kk) {
    const u16* s = gB0 + t * 64 + kk * 32;
    __builtin_amdgcn_global_load_lds(
        (const __attribute__((address_space(1))) void*)s,
        (__attribute__((address_space(3))) void*)&Bs[t & 1][kk][dst0], 16, 0, 0);
    __builtin_amdgcn_global_load_lds(
        (const __attribute__((address_space(1))) void*)(s + (size_t)128 * K),
        (__attribute__((address_space(3))) void*)&Bs[t & 1][kk][dst0 + 4096], 16, 0, 0);
  };

  const int fr = l & 15, g = l >> 4;
  const int slot = (g ^ ((fr >> 1) & 3)) * 16;
  const int aoff = (wr * 128 + fr) * 64 + slot;
  const int boff = (wc * 64 + fr) * 64 + slot;

  bf16x8 af[4], bfc[4];
  auto rdA = [&](int buf, int kk, int mlo) {
    const char* base = (const char*)&As[buf][kk][0];
    #pragma unroll
    for (int m = 0; m < 4; ++m)
      af[m] = *(const bf16x8*)(base + aoff + (mlo + m) * 1024);
  };
  auto rdB = [&](int buf, int kk) {
    const char* base = (const char*)&Bs[buf][kk][0];
    #pragma unroll
    for (int n = 0; n < 4; ++n)
      bfc[n] = *(const bf16x8*)(base + boff + n * 1024);
  };

  f32x4 accLo[4][4] = {};
  f32x4 accHi[4][4] = {};

  stgA(0, 0); stgB(0, 0); stgA(0, 1); stgB(0, 1);
  stgA(1, 0); stgB(1, 0); stgB(1, 1);
  VM6;
  BARR;

  for (int t = 0; t < nkt; ++t) {
    const int buf = t & 1;
    const bool s1 = (t + 1 < nkt);
    const bool s2 = (t + 2 < nkt);
    rdA(buf, 0, 0); rdB(buf, 0);
    if (s1) stgA(t + 1, 1);
    BARR; MM(accLo); BARR;
    rdA(buf, 0, 4);
    if (s2) stgB(t + 2, 0);
    BARR; MM(accHi); BARR;
    rdA(buf, 1, 0); rdB(buf, 1);
    if (s2) stgA(t + 2, 0);
    BARR; MM(accLo); BARR;
    rdA(buf, 1, 4);
    if (s2) stgB(t + 2, 1);
    BARR; MM(accHi);
    if (s2)      { VM6; BARR; }
    else if (s1) { VM0; BARR; }
  }

  const int ccol0 = bx * 256 + wc * 64;
  const int row0 = by * 256 + wr * 128 + g * 4;
  if (MODE == 0) {
    #pragma unroll
    for (int n = 0; n < 4; ++n) {
      int col = ccol0 + n * 16 + fr;
      float bv = bias[col];
      #pragma unroll
      for (int m = 0; m < 4; ++m)
        #pragma unroll
        for (int r = 0; r < 4; ++r) {
          float v0 = fmaxf(accLo[m][n][r] + bv, 0.f);
          C[(size_t)(row0 + m * 16 + r) * N + col] = f2bf_bits(v0);
          float v1 = fmaxf(accHi[m][n][r] + bv, 0.f);
          C[(size_t)(row0 + 64 + m * 16 + r) * N + col] = f2bf_bits(v1);
        }
    }
  } else {
    float bv[4], wv[4];
    #pragma unroll
    for (int n = 0; n < 4; ++n) {
      int col = ccol0 + n * 16 + fr;
      bv[n] = bias[col]; wv[n] = Wout[col];
    }
    float* pbase = part + (size_t)(bx * 4 + wc) * B_;
    #pragma unroll
    for (int m = 0; m < 4; ++m)
      #pragma unroll
      for (int r = 0; r < 4; ++r) {
        float s0 = 0.f, s1v = 0.f;
        #pragma unroll
        for (int n = 0; n < 4; ++n) {
          s0  = fmaf(fmaxf(accLo[m][n][r] + bv[n], 0.f), wv[n], s0);
          s1v = fmaf(fmaxf(accHi[m][n][r] + bv[n], 0.f), wv[n], s1v);
        }
        s0 += __shfl_xor(s0, 1); s0 += __shfl_xor(s0, 2);
        s0 += __shfl_xor(s0, 4); s0 += __shfl_xor(s0, 8);
        s1v += __shfl_xor(s1v, 1); s1v += __shfl_xor(s1v, 2);
        s1v += __shfl_xor(s1v, 4); s1v += __shfl_xor(s1v, 8);
        if (fr == 0) {
          pbase[row0 + m * 16 + r] = s0;
          pbase[row0 + 64 + m * 16 + r] = s1v;
        }
      }
  }
}

// out[b] = tail[b] + sum_{j<16} part[j][b]
__global__ __launch_bounds__(256) void final_sum(const float* __restrict__ tail,
                                                 const float* __restrict__ part,
                                                 float* __restrict__ out) {
  int b = blockIdx.x * 256 + threadIdx.x;
  float s = tail[b];
  #pragma unroll
  for (int j = 0; j < 16; ++j) s += part[(size_t)j * B_ + b];
  out[b] = s;
}

extern "C" void kernel_launch(void* const* d_in, const int* in_sizes, int n_in,
                              void* d_out, int out_size, void* d_ws, size_t ws_size,
                              hipStream_t stream) {
  const int*   Xi   = (const int*)d_in[0];
  const float* Xv   = (const float*)d_in[1];
  const float* emb  = (const float*)d_in[2];
  const float* cw   = (const float*)d_in[3];
  const float* cb   = (const float*)d_in[4];
  const float* W1   = (const float*)d_in[5];
  const float* b1   = (const float*)d_in[6];
  const float* W2   = (const float*)d_in[7];
  const float* b2   = (const float*)d_in[8];
  const float* Wout = (const float*)d_in[9];
  const float* bout = (const float*)d_in[10];
  float* out = (float*)d_out;

  char* ws = (char*)d_ws;
  size_t off = 0;
  auto alloc = [&](size_t bytes) {
    void* p = ws + off; off += (bytes + 255) & ~(size_t)255; return p;
  };
  u16*   x0b  = (u16*)  alloc((size_t)B_ * KP1_ * 2);
  u16*   w1bt = (u16*)  alloc((size_t)H_ * KP1_ * 2);
  u16*   w2bt = (u16*)  alloc((size_t)H_ * H_ * 2);
  u16*   h1   = (u16*)  alloc((size_t)B_ * H_ * 2);
  float* tail = (float*)alloc((size_t)B_ * 4);
  float* part = (float*)alloc((size_t)16 * B_ * 4);

  hipLaunchKernelGGL(fused_front, dim3(B_ / 4 + 112 + 256), dim3(256), 0, stream,
                     Xi, Xv, emb, cw, cb, Wout, bout, W1, W2, x0b, w1bt, w2bt, tail);
  // MEASUREMENT ROUND: GEMM pair launched 4x (idempotent). G_pair ~= (dur - 97) / 3.
  for (int rep = 0; rep < 4; ++rep) {
    hipLaunchKernelGGL((gemm256<0>), dim3((B_ / 256) * (H_ / 256)), dim3(512), 0, stream,
                       x0b, w1bt, b1, h1, nullptr, nullptr, H_, KP1_);
    hipLaunchKernelGGL((gemm256<1>), dim3((B_ / 256) * (H_ / 256)), dim3(512), 0, stream,
                       h1, w2bt, b2, nullptr, Wout, part, H_, H_);
  }
  hipLaunchKernelGGL(final_sum, dim3(B_ / 256), dim3(256), 0, stream, tail, part, out);
}

// Round 11
// 93.528 us; speedup vs baseline: 3.0776x; 3.0776x over previous
//
#include <hip/hip_runtime.h>
#include <hip/hip_bf16.h>

#define B_   16384
#define F_   26
#define N_   100000
#define M_   16
#define NUM_ 13
#define D_   429
#define KP1_ 448     // padded K for GEMM1, multiple of 64
#define KB1_ 14      // KP1_/32 k-blocks
#define KB2_ 32      // H_/32
#define L_   6
#define H_   1024

typedef unsigned short u16;
typedef __bf16 bf16x8 __attribute__((ext_vector_type(8)));
typedef float  f32x4  __attribute__((ext_vector_type(4)));

__device__ __forceinline__ u16 f2bf_bits(float f) {
  union { float f; unsigned u; } x; x.f = f;
  unsigned r = x.u + 0x7FFFu + ((x.u >> 16) & 1u);   // RNE
  return (u16)(r >> 16);
}

// Fused front kernel.
// Blocks [0, 4096): gather -> x0 -> bf16 row -> CrossNet -> out[b] = tail
// Blocks [4096, +112): W1 -> w1f FRAGMENT-MAJOR bf16 [n_frag][kb][lane][8]
// Blocks [+112, +368): W2 -> w2f FRAGMENT-MAJOR bf16
// frag layout: element (n_frag, kb, lane, j) = W[kb*32 + (lane>>4)*8 + j][n_frag*16 + (lane&15)]
__global__ __launch_bounds__(256) void fused_front(
    const int* __restrict__ Xi, const float* __restrict__ Xv,
    const float* __restrict__ emb,
    const float* __restrict__ cw, const float* __restrict__ cb,
    const float* __restrict__ Wout, const float* __restrict__ bout,
    const float* __restrict__ W1, const float* __restrict__ W2,
    u16* __restrict__ x0b, u16* __restrict__ w1f, u16* __restrict__ w2f,
    float* __restrict__ out) {
  __shared__ __align__(16) u16 sbuf[4][KP1_];
  __shared__ __align__(16) float tile[64][68];
  const int blk = blockIdx.x;
  const int tid = threadIdx.x;
  if (blk < B_ / 4) {
    const int w = tid >> 6, lane = tid & 63;
    const int b = blk * 4 + w;
    const int* xi = Xi + b * F_;

    float x0r[7];
    #pragma unroll
    for (int i = 0; i < 7; ++i) {
      int e = i * 64 + lane;
      float v = 0.f;
      if (e < 416) {
        int f = e >> 4;
        int idx = xi[f];
        v = emb[((size_t)f * N_ + idx) * M_ + (e & 15)];
      } else if (e < D_) {
        v = Xv[b * NUM_ + (e - 416)];
      }
      x0r[i] = v;
      sbuf[w][e] = f2bf_bits(v);
    }

    float xr[7];
    #pragma unroll
    for (int i = 0; i < 7; ++i) xr[i] = x0r[i];
    for (int l = 0; l < L_; ++l) {
      float wl[7], bl[7];
      #pragma unroll
      for (int i = 0; i < 7; ++i) {
        int e = i * 64 + lane;
        if (e < D_) {
          int d = (e < 416) ? (13 + e) : (e - 416);
          wl[i] = cw[l * D_ + d]; bl[i] = cb[l * D_ + d];
        } else { wl[i] = 0.f; bl[i] = 0.f; }
      }
      float s = 0.f;
      #pragma unroll
      for (int i = 0; i < 7; ++i) s += xr[i] * wl[i];
      #pragma unroll
      for (int off = 32; off; off >>= 1) s += __shfl_xor(s, off);
      #pragma unroll
      for (int i = 0; i < 7; ++i) xr[i] = x0r[i] * s + bl[i] + xr[i];
    }

    __syncthreads();
    if (lane < 56)
      ((uint4*)(x0b + (size_t)b * KP1_))[lane] = ((const uint4*)sbuf[w])[lane];

    float s = 0.f;
    #pragma unroll
    for (int i = 0; i < 7; ++i) {
      int e = i * 64 + lane;
      if (e < D_) {
        int d = (e < 416) ? (13 + e) : (e - 416);
        s += xr[i] * Wout[H_ + d];
      }
    }
    #pragma unroll
    for (int off = 32; off; off >>= 1) s += __shfl_xor(s, off);
    if (lane == 0) out[b] = s + bout[0];
  } else {
    int pid = blk - B_ / 4;
    u16* dstbuf;
    int ti, tj, KB;
    bool isW1;
    if (pid < 112) { isW1 = true;  ti = pid >> 4; tj = pid & 15; KB = KB1_; dstbuf = w1f; }
    else { pid -= 112; isW1 = false; ti = pid >> 4; tj = pid & 15; KB = KB2_; dstbuf = w2f; }
    const int k0 = ti * 64, c0 = tj * 64;
    #pragma unroll
    for (int it = 0; it < 4; ++it) {
      int kl = it * 16 + (tid >> 4);
      float4 v;
      if (isW1) {
        int e = k0 + kl;
        int d = (e < 416) ? (13 + e) : ((e < D_) ? (e - 416) : -1);
        v = make_float4(0.f, 0.f, 0.f, 0.f);
        if (d >= 0) v = *(const float4*)&W1[(size_t)d * H_ + c0 + (tid & 15) * 4];
      } else {
        v = *(const float4*)&W2[(size_t)(k0 + kl) * H_ + c0 + (tid & 15) * 4];
      }
      *(float4*)&tile[kl][(tid & 15) * 4] = v;
    }
    __syncthreads();
    // fragment-major emit: 8 (nf,kb) pairs x 64 lanes x 16B = 8KB
    #pragma unroll
    for (int s = 0; s < 2; ++s) {
      int slot = s * 256 + tid;
      int pair = slot >> 6;
      int lane = slot & 63;
      int nf_l = pair >> 1, kb_l = pair & 1;
      u16 tmp[8];
      #pragma unroll
      for (int j = 0; j < 8; ++j)
        tmp[j] = f2bf_bits(tile[kb_l * 32 + (lane >> 4) * 8 + j][nf_l * 16 + (lane & 15)]);
      size_t off = ((((size_t)(tj * 4 + nf_l)) * KB + (ti * 2 + kb_l)) * 64 + lane) * 8;
      *(uint4*)&dstbuf[off] = *(uint4*)tmp;
    }
  }
}

#define BARR __builtin_amdgcn_s_barrier()
#define SBR  __builtin_amdgcn_sched_barrier(0)
#define VM8  asm volatile("s_waitcnt vmcnt(8)" ::: "memory")
#define MMQ(ACC, BB, KK) do { \
  __builtin_amdgcn_s_setprio(1); \
  _Pragma("unroll") \
  for (int mi = 0; mi < 4; ++mi) { \
    _Pragma("unroll") \
    for (int ni = 0; ni < 4; ++ni) \
      ACC[mi][ni] = __builtin_amdgcn_mfma_f32_16x16x32_bf16(af[mi], BB[KK][ni], ACC[mi][ni], 0, 0, 0); \
  } \
  __builtin_amdgcn_s_setprio(0); \
} while (0)

// 256x256 tile, BK=64, 8 waves (2x4).
// A: LDS double-buffer (2x32KB), gload_lds + swizzle (as r7).
// B: DIRECT global->VGPR from FRAGMENT-MAJOR layout (each frag load = one
//    coalesced 1KB global_load_dwordx4 from L2-resident weights), register
//    double-buffered bE/bO one tile ahead.
// Sync: ONE vmcnt(8) + ONE barrier per K-tile. Counter chain: MFMA's auto-wait
// on bE drains loadB(t) to 8 outstanding; VM8 then exactly drains stgA(t+1).
// SBR pins stgA-before-loadB issue order so the count is exact.
// LDS traffic/tile: 128KB reads + 32KB writes (was 192+64) -> near MFMA-balanced.
// MODE 0: C = bf16(relu(A@Bf + bias)).  MODE 1: out[row] += sum_col relu(.)*Wout[col].
template<int MODE>
__global__ __launch_bounds__(512, 2) void gemm256(
    const u16* __restrict__ A, const u16* __restrict__ Bf,
    const float* __restrict__ bias, u16* __restrict__ C,
    const float* __restrict__ Wout, float* __restrict__ out,
    int N, int K) {
  __shared__ __align__(16) u16 As[2][2][256 * 32];
  const int nbx = N >> 8;
  const int cpx = gridDim.x >> 3;
  const int swz = (blockIdx.x & 7) * cpx + (blockIdx.x >> 3);
  const int bx = swz % nbx;
  const int by = swz / nbx;
  const int tid = threadIdx.x;
  const int l = tid & 63;
  const int w = tid >> 6;
  const int wr = w >> 2, wc = w & 3;
  const int nkt = K >> 6;         // 7 for K=448, 16 for K=1024
  const int KB = K >> 5;          // k-blocks in frag layout

  // A staging (unchanged from r7): source pre-swizzled chunk^((row>>1)&3)
  const int sr = tid >> 2;
  const int scs = ((tid & 3) ^ ((tid >> 3) & 3)) * 8;
  const u16* gA0 = A + (size_t)(by * 256 + sr) * K + scs;
  const int dst0 = tid * 8;

  auto stgA = [&](int t) {   // 4 gload_lds (both kk, both row-halves)
    const u16* s = gA0 + t * 64;
    #pragma unroll
    for (int kk = 0; kk < 2; ++kk)
      #pragma unroll
      for (int i = 0; i < 2; ++i)
        __builtin_amdgcn_global_load_lds(
            (const __attribute__((address_space(1))) void*)(s + kk * 32 + (size_t)i * 128 * K),
            (__attribute__((address_space(3))) void*)&As[t & 1][kk][dst0 + i * 4096], 16, 0, 0);
  };

  // B direct: frag-major [n_frag][kb][lane][8]
  const u16* Bw = Bf + ((size_t)(bx * 16 + wc * 4) * KB) * 512 + (size_t)l * 8;
  auto loadB = [&](int t, bf16x8 (&bb)[2][4]) {
    #pragma unroll
    for (int kk = 0; kk < 2; ++kk)
      #pragma unroll
      for (int n = 0; n < 4; ++n)
        bb[kk][n] = *(const bf16x8*)(Bw + ((size_t)n * KB + (2 * t + kk)) * 512);
  };

  // A fragment reads (swizzled slot, bank-optimal)
  const int fr = l & 15, g = l >> 4;
  const int slot = (g ^ ((fr >> 1) & 3)) * 16;
  const int aoff = (wr * 128 + fr) * 64 + slot;
  bf16x8 af[4];
  auto rdA = [&](int buf, int kk, int mlo) {
    const char* base = (const char*)&As[buf][kk][0];
    #pragma unroll
    for (int m = 0; m < 4; ++m)
      af[m] = *(const bf16x8*)(base + aoff + (mlo + m) * 1024);
  };

  f32x4 accLo[4][4] = {};
  f32x4 accHi[4][4] = {};
  bf16x8 bE[2][4], bO[2][4];

  stgA(0);
  SBR;
  loadB(0, bE);
  VM8;            // 12 outstanding -> drain the 4 A-loads
  BARR;

  for (int t = 0; t < nkt; t += 2) {
    // ---- even tile t (A buf0, bE)
    {
      const bool s1 = (t + 1 < nkt);
      if (s1) { stgA(t + 1); SBR; loadB(t + 1, bO); }
      rdA(0, 0, 0); MMQ(accLo, bE, 0);
      rdA(0, 0, 4); MMQ(accHi, bE, 0);
      rdA(0, 1, 0); MMQ(accLo, bE, 1);
      rdA(0, 1, 4); MMQ(accHi, bE, 1);
      if (s1) { VM8; BARR; }
    }
    // ---- odd tile t+1 (A buf1, bO)
    if (t + 1 < nkt) {
      const bool s2 = (t + 2 < nkt);
      if (s2) { stgA(t + 2); SBR; loadB(t + 2, bE); }
      rdA(1, 0, 0); MMQ(accLo, bO, 0);
      rdA(1, 0, 4); MMQ(accHi, bO, 0);
      rdA(1, 1, 0); MMQ(accLo, bO, 1);
      rdA(1, 1, 4); MMQ(accHi, bO, 1);
      if (s2) { VM8; BARR; }
    }
  }

  const int ccol0 = bx * 256 + wc * 64;
  const int row0 = by * 256 + wr * 128 + g * 4;
  if (MODE == 0) {
    #pragma unroll
    for (int n = 0; n < 4; ++n) {
      int col = ccol0 + n * 16 + fr;
      float bv = bias[col];
      #pragma unroll
      for (int m = 0; m < 4; ++m)
        #pragma unroll
        for (int r = 0; r < 4; ++r) {
          float v0 = fmaxf(accLo[m][n][r] + bv, 0.f);
          C[(size_t)(row0 + m * 16 + r) * N + col] = f2bf_bits(v0);
          float v1 = fmaxf(accHi[m][n][r] + bv, 0.f);
          C[(size_t)(row0 + 64 + m * 16 + r) * N + col] = f2bf_bits(v1);
        }
    }
  } else {
    float bv[4], wv[4];
    #pragma unroll
    for (int n = 0; n < 4; ++n) {
      int col = ccol0 + n * 16 + fr;
      bv[n] = bias[col]; wv[n] = Wout[col];
    }
    #pragma unroll
    for (int m = 0; m < 4; ++m)
      #pragma unroll
      for (int r = 0; r < 4; ++r) {
        float s0 = 0.f, s1v = 0.f;
        #pragma unroll
        for (int n = 0; n < 4; ++n) {
          s0  = fmaf(fmaxf(accLo[m][n][r] + bv[n], 0.f), wv[n], s0);
          s1v = fmaf(fmaxf(accHi[m][n][r] + bv[n], 0.f), wv[n], s1v);
        }
        s0 += __shfl_xor(s0, 1); s0 += __shfl_xor(s0, 2);
        s0 += __shfl_xor(s0, 4); s0 += __shfl_xor(s0, 8);
        s1v += __shfl_xor(s1v, 1); s1v += __shfl_xor(s1v, 2);
        s1v += __shfl_xor(s1v, 4); s1v += __shfl_xor(s1v, 8);
        if (fr == 0) {
          atomicAdd(out + row0 + m * 16 + r, s0);
          atomicAdd(out + row0 + 64 + m * 16 + r, s1v);
        }
      }
  }
}

extern "C" void kernel_launch(void* const* d_in, const int* in_sizes, int n_in,
                              void* d_out, int out_size, void* d_ws, size_t ws_size,
                              hipStream_t stream) {
  const int*   Xi   = (const int*)d_in[0];
  const float* Xv   = (const float*)d_in[1];
  const float* emb  = (const float*)d_in[2];
  const float* cw   = (const float*)d_in[3];
  const float* cb   = (const float*)d_in[4];
  const float* W1   = (const float*)d_in[5];
  const float* b1   = (const float*)d_in[6];
  const float* W2   = (const float*)d_in[7];
  const float* b2   = (const float*)d_in[8];
  const float* Wout = (const float*)d_in[9];
  const float* bout = (const float*)d_in[10];
  float* out = (float*)d_out;

  char* ws = (char*)d_ws;
  size_t off = 0;
  auto alloc = [&](size_t bytes) {
    void* p = ws + off; off += (bytes + 255) & ~(size_t)255; return p;
  };
  u16* x0b = (u16*)alloc((size_t)B_ * KP1_ * 2);
  u16* w1f = (u16*)alloc((size_t)H_ * KP1_ * 2);
  u16* w2f = (u16*)alloc((size_t)H_ * H_ * 2);
  u16* h1  = (u16*)alloc((size_t)B_ * H_ * 2);

  hipLaunchKernelGGL(fused_front, dim3(B_ / 4 + 112 + 256), dim3(256), 0, stream,
                     Xi, Xv, emb, cw, cb, Wout, bout, W1, W2, x0b, w1f, w2f, out);
  hipLaunchKernelGGL((gemm256<0>), dim3((B_ / 256) * (H_ / 256)), dim3(512), 0, stream,
                     x0b, w1f, b1, h1, nullptr, nullptr, H_, KP1_);
  hipLaunchKernelGGL((gemm256<1>), dim3((B_ / 256) * (H_ / 256)), dim3(512), 0, stream,
                     h1, w2f, b2, nullptr, Wout, out, H_, H_);
}